// Round 8
// baseline (556.115 us; speedup 1.0000x reference)
//
#include <hip/hip_runtime.h>

// B=4, T=4096, D=A=1024.  All-MFMA bf16 pipeline, BK=64 async staging.
// R18: R14 config restored (455us verified: 2-barrier BK=64 loops, balanced
//   grids, 0-conflict rotation swizzle, o_gemm 128x128 @4 blocks/CU) +
//   softmax FUSED into o_gemm (G=4 path):
//     stats_rows : softmax_rows minus the P write-back -- computes per-row
//                  (m, 1/s) with IDENTICAL reduction order, writes float2
//                  into the dead qb region (Q/K unused after s_gemm_v).
//     o_gemm_fused : stages raw S (same DMA), applies P = f2bf(exp(v-m)*inv)
//                  in-register on A-fragments (same op sequence as legacy
//                  softmax => bit-identical P), causal mask only in the last
//                  two K-steps (block-uniform branch), 4 rows' stats/lane.
//   Saves the 69MB P write + ~30us kernel time + one launch gap.
//   R17 lesson (3rd confirmation): blocks/CU beats per-block efficiency in
//   this 2-barrier structure -- o_gemm 128x256 @2 blocks/CU ran 158us vs
//   ~95us @128x128 4/CU.  G<4 fallback keeps legacy softmax+o_gemm.
// Rotation swizzle (verified 0 conflicts, 64-elem rows): logical granule g
//   of tile-row R stored at (g+R)&7; reads co=(h*32)^(((qq+r)&7)<<3);
//   staging source granule ((tid&7)-(tid>>3))&7; DMA dest linear lane*16B.
// Packed S: row-block y128 at elem offset y128(y128+1)/2*16384, ld (y128+1)*128.
// ws: Q 32MB (stats aliases here after s_gemm_v) | K 32MB | Vt 32MB | S G*17.3MB
// d_out (64MB) doubles as Xb(32MB)+Wb(6MB) scratch during projection.

#define T_SEQ 4096
#define DA    1024
#define BATCH 4
#define M_TOT (BATCH * T_SEQ)            // 16384
#define SB_ELEMS 8650752                  // 528 tri-blocks * 16384 elems

typedef float  f32x4  __attribute__((ext_vector_type(4)));
typedef short  bf16x8 __attribute__((ext_vector_type(8)));

static __device__ __forceinline__ unsigned short f2bf(float f) {
    unsigned u = __builtin_bit_cast(unsigned, f);
    u += 0x7FFFu + ((u >> 16) & 1u);      // RNE
    return (unsigned short)(u >> 16);
}
static __device__ __forceinline__ unsigned pack2(float a, float b) {
    return (unsigned)f2bf(a) | ((unsigned)f2bf(b) << 16);
}
static __device__ __forceinline__ float bflo(unsigned u) {
    return __builtin_bit_cast(float, u << 16);
}
static __device__ __forceinline__ float bfhi(unsigned u) {
    return __builtin_bit_cast(float, u & 0xFFFF0000u);
}
static __device__ __forceinline__ float bfu(unsigned short u) {
    return __builtin_bit_cast(float, (unsigned)u << 16);
}

// async global->LDS, 16 B per lane; LDS dest = wave-uniform base + lane*16
#define GLOAD_LDS16(g, l)                                                   \
    __builtin_amdgcn_global_load_lds(                                       \
        (const __attribute__((address_space(1))) void*)(g),                 \
        (__attribute__((address_space(3))) void*)(l), 16, 0, 0)

// source-granule pre-permute for the rotation swizzle (64-elem rows)
#define STAGE_SCG  (((((tid & 7) - (tid >> 3)) & 7)) * 8)

// ---------------------------------------------------------------------------
// MFMA core: per wave 64x64 out of Xs rows [wm*64,+64), Ws [wn*64,+64)
// ---------------------------------------------------------------------------
static __device__ __forceinline__ void mfma_step(
    const unsigned short* __restrict__ Xs, const unsigned short* __restrict__ Ws,
    int wm, int wn, int qq, int r, int swz, f32x4 acc[4][4])
{
    #pragma unroll
    for (int h = 0; h < 2; ++h) {
        const int co = (h * 32) ^ swz;            // qq folded into swz
        bf16x8 a[4], b[4];
        #pragma unroll
        for (int i = 0; i < 4; ++i)
            a[i] = *(const bf16x8*)&Xs[(wm * 64 + i * 16 + r) * 64 + co];
        #pragma unroll
        for (int j = 0; j < 4; ++j)
            b[j] = *(const bf16x8*)&Ws[(wn * 64 + j * 16 + r) * 64 + co];
        #pragma unroll
        for (int i = 0; i < 4; ++i)
            #pragma unroll
            for (int j = 0; j < 4; ++j)
                acc[i][j] = __builtin_amdgcn_mfma_f32_16x16x32_bf16(
                    a[i], b[j], acc[i][j], 0, 0, 0);
    }
}

// ---------------------------------------------------------------------------
// 256-thread K-loop: 128x64 A + 128x64 B tiles (legacy o_gemm).
// ---------------------------------------------------------------------------
static __device__ __forceinline__ void k_loop_256(
    const unsigned short* __restrict__ A, int lda,
    const unsigned short* __restrict__ B, int ldb,
    int m0, int n0, int K,
    unsigned short* __restrict__ Xs, unsigned short* __restrict__ Ws,
    int tid, int wm, int wn, int qq, int r, int swz, f32x4 acc[4][4])
{
    const int srow = tid >> 3;                              // 0..31
    const int scg  = STAGE_SCG;
    const unsigned short* ga = A + (size_t)(m0 + srow) * lda + scg;
    const unsigned short* gb = B + (size_t)(n0 + srow) * ldb + scg;
    unsigned short* la = Xs + tid * 8;
    unsigned short* lb = Ws + tid * 8;
    const size_t astep = (size_t)32 * lda;
    const size_t bstep = (size_t)32 * ldb;

    for (int k0 = 0; k0 < K; k0 += 64) {
        const unsigned short* pa = ga;
        const unsigned short* pb = gb;
        #pragma unroll
        for (int p = 0; p < 4; ++p) {
            GLOAD_LDS16(pa, la + p * 2048);
            GLOAD_LDS16(pb, lb + p * 2048);
            pa += astep;
            pb += bstep;
        }
        ga += 64;
        gb += 64;
        __syncthreads();
        mfma_step(Xs, Ws, wm, wn, qq, r, swz, acc);
        __syncthreads();
    }
}

// ---------------------------------------------------------------------------
// 512-thread K-loop: 256x64 A + 128x64 B tiles (proj/s_gemm_v).
// ---------------------------------------------------------------------------
static __device__ __forceinline__ void k_loop_512(
    const unsigned short* __restrict__ A, int lda,
    const unsigned short* __restrict__ B, int ldb,
    int m0, int n0, int K,
    unsigned short* __restrict__ Xs, unsigned short* __restrict__ Ws,
    int tid, int wm, int wn, int qq, int r, int swz, f32x4 acc[4][4])
{
    const int srow = tid >> 3;                              // 0..63
    const int scg  = STAGE_SCG;
    const unsigned short* ga = A + (size_t)(m0 + srow) * lda + scg;
    const unsigned short* gb = B + (size_t)(n0 + srow) * ldb + scg;
    unsigned short* la = Xs + tid * 8;
    unsigned short* lb = Ws + tid * 8;
    const size_t astep = (size_t)64 * lda;
    const size_t bstep = (size_t)64 * ldb;

    for (int k0 = 0; k0 < K; k0 += 64) {
        const unsigned short* pa = ga;
        #pragma unroll
        for (int p = 0; p < 4; ++p) {           // A: 4 x 64 rows = 256
            GLOAD_LDS16(pa, la + p * 4096);
            pa += astep;
        }
        const unsigned short* pb = gb;
        #pragma unroll
        for (int p = 0; p < 2; ++p) {           // B: 2 x 64 rows = 128
            GLOAD_LDS16(pb, lb + p * 4096);
            pb += bstep;
        }
        ga += 64;
        gb += 64;
        __syncthreads();
        mfma_step(Xs, Ws, wm, wn, qq, r, swz, acc);
        __syncthreads();
    }
}

#define GEMM_VARS                                                            \
    const int tid  = threadIdx.x;                                            \
    const int wave = tid >> 6;                                               \
    const int lane = tid & 63;                                               \
    const int wm   = wave >> 1;                                              \
    const int wn   = wave & 1;                                               \
    const int qq   = lane >> 4;                                              \
    const int r    = lane & 15;                                              \
    const int swz  = ((qq + r) & 7) << 3;                                    \
    f32x4 acc[4][4];                                                         \
    _Pragma("unroll")                                                        \
    for (int i = 0; i < 4; ++i)                                              \
        _Pragma("unroll")                                                    \
        for (int j = 0; j < 4; ++j)                                          \
            acc[i][j] = f32x4{0.f, 0.f, 0.f, 0.f};

#define GEMM_PROLOGUE_256                                                    \
    __shared__ unsigned short Xs[8192];                                      \
    __shared__ unsigned short Ws[8192];                                      \
    GEMM_VARS

#define GEMM_PROLOGUE_512                                                    \
    __shared__ unsigned short Xs[16384];                                     \
    __shared__ unsigned short Ws[8192];                                      \
    GEMM_VARS

// C/D layout: col = lane&15, row = (lane>>4)*4 + reg   (row within wave tile)
#define EPILOGUE_LOOP(BODY)                                                  \
    _Pragma("unroll")                                                        \
    for (int i = 0; i < 4; ++i)                                              \
        _Pragma("unroll")                                                    \
        for (int j = 0; j < 4; ++j)                                          \
            _Pragma("unroll")                                                \
            for (int rr = 0; rr < 4; ++rr) {                                 \
                const int row = wm * 64 + i * 16 + qq * 4 + rr;              \
                const int col = wn * 64 + j * 16 + r;                        \
                const float val = acc[i][j][rr];                             \
                BODY                                                         \
            }

// transposed V epilogue: rows rg0..rg0+3 are consecutive t -> one ushort4
#define EPILOGUE_VT(VT, M0, NC)                                              \
    _Pragma("unroll")                                                        \
    for (int i = 0; i < 4; ++i)                                              \
        _Pragma("unroll")                                                    \
        for (int j = 0; j < 4; ++j) {                                        \
            const int rg0 = (M0) + wm * 64 + i * 16 + qq * 4;                \
            const int col = wn * 64 + j * 16 + r;                            \
            const int bb  = rg0 >> 12;                                       \
            const int tt  = rg0 & 4095;                                      \
            ushort4 pkv;                                                     \
            pkv.x = f2bf(acc[i][j][0]); pkv.y = f2bf(acc[i][j][1]);          \
            pkv.z = f2bf(acc[i][j][2]); pkv.w = f2bf(acc[i][j][3]);          \
            *(ushort4*)&(VT)[((size_t)bb << 22) +                            \
                             (size_t)((NC) + col) * 4096 + tt] = pkv;        \
        }

// ---------------------------------------------------------------------------
// fp32 -> bf16 conversion. Blocks 0..8191: X. Blocks 8192..9727: Wq|Wk|Wv.
// ---------------------------------------------------------------------------
__global__ __launch_bounds__(256) void to_bf16_all(
    const float* __restrict__ X, const float* __restrict__ Wq,
    const float* __restrict__ Wk, const float* __restrict__ Wv,
    unsigned short* __restrict__ Xb, unsigned short* __restrict__ Wb)
{
    const int bx = blockIdx.x;
    const float* src;
    unsigned short* dst;
    size_t off;
    if (bx < 8192) {
        src = X; dst = Xb; off = (size_t)bx * 2048;
    } else {
        const int s   = bx - 8192;
        const int seg = s >> 9;
        src = (seg == 0) ? Wq : (seg == 1) ? Wk : Wv;
        dst = Wb + (size_t)seg * (DA * DA);
        off = (size_t)(s & 511) * 2048;
    }
    const size_t i = off + (size_t)threadIdx.x * 8;
    const float4 v0 = *(const float4*)(src + i);
    const float4 v1 = *(const float4*)(src + i + 4);
    uint4 pk;
    pk.x = pack2(v0.x, v0.y); pk.y = pack2(v0.z, v0.w);
    pk.z = pack2(v1.x, v1.y); pk.w = pack2(v1.z, v1.w);
    *(uint4*)(dst + i) = pk;
}

// ---------------------------------------------------------------------------
// Q,K projections, 256x128 tiles. Wb = [3*1024][1024]. 1024 blocks,
// XCD-swizzled: xcd owns mt band [xcd*8, xcd*8+8), n fastest.
// ---------------------------------------------------------------------------
__global__ __launch_bounds__(512) void proj_qk(
    const unsigned short* __restrict__ Xb, const unsigned short* __restrict__ Wb,
    unsigned short* __restrict__ qb, unsigned short* __restrict__ kb)
{
    const int li   = blockIdx.x;
    const int xcd  = li & 7;
    const int slot = li >> 3;            // 0..127
    const int mt   = xcd * 8 + (slot >> 4);
    const int nt   = slot & 15;          // 0..15 across Wq|Wk
    const int m0   = mt * 256;

    GEMM_PROLOGUE_512
    k_loop_512(Xb, DA, Wb, DA, m0, nt * 128, DA, Xs, Ws,
               tid, wm, wn, qq, r, swz, acc);

    unsigned short* Y = (nt >> 3) ? kb : qb;
    const int nc = (nt & 7) * 128;
    EPILOGUE_LOOP({
        Y[(size_t)(m0 + row) * DA + (nc + col)] = f2bf(val);
    })
}

// ---------------------------------------------------------------------------
// Fallback V projection (only if workspace forces G<4). 512 blocks, 256x128.
// ---------------------------------------------------------------------------
__global__ __launch_bounds__(512) void proj_v(
    const unsigned short* __restrict__ Xb, const unsigned short* __restrict__ Wb,
    unsigned short* __restrict__ vt)
{
    const int li = blockIdx.x;           // 0..511
    const int m0 = (li >> 3) * 256;
    const int n0 = (li & 7) * 128;
    GEMM_PROLOGUE_512
    k_loop_512(Xb, DA, Wb + (size_t)2048 * DA, DA, m0, n0, DA, Xs, Ws,
               tid, wm, wn, qq, r, swz, acc);
    EPILOGUE_VT(vt, m0, n0)
}

// ---------------------------------------------------------------------------
// S = Q.K^T / 32 (lower-tri, packed) with V tiles on dead upper slots.
// Flat active-only grid (272 + vPerZ, G), 512 threads, 256x128 tiles.
// ---------------------------------------------------------------------------
__global__ __launch_bounds__(512) void s_gemm_v(
    const unsigned short* __restrict__ qb, const unsigned short* __restrict__ kb,
    const unsigned short* __restrict__ Xb, const unsigned short* __restrict__ Wb,
    unsigned short* __restrict__ sbuf, unsigned short* __restrict__ vt,
    int bbase, int vPerZ)
{
    const int t  = blockIdx.x;
    const int bz = blockIdx.y;
    const bool isS = (t < 272);

    const unsigned short *Am, *Bm;
    int m0, n0;
    if (isS) {
        int yr = (int)((__fsqrt_rn(4.f * (float)t + 1.f) - 1.f) * 0.5f);
        while ((yr + 1) * (yr + 2) <= t) ++yr;      // exact fixup
        while (yr * (yr + 1) > t) --yr;
        const int x = t - yr * (yr + 1);
        const int b = bbase + bz;
        Am = qb + (size_t)b * T_SEQ * DA;
        Bm = kb + (size_t)b * T_SEQ * DA;
        m0 = yr * 256;
        n0 = x * 128;
    } else {
        const int vid = bz * vPerZ + (t - 272);      // 0..511
        Am = Xb;
        Bm = Wb + (size_t)2048 * DA;
        m0 = (vid >> 3) * 256;
        n0 = (vid & 7) * 128;
    }

    GEMM_PROLOGUE_512
    k_loop_512(Am, DA, Bm, DA, m0, n0, DA, Xs, Ws,
               tid, wm, wn, qq, r, swz, acc);

    if (isS) {
        unsigned short* Sz = sbuf + (size_t)bz * SB_ELEMS;
        EPILOGUE_LOOP({
            const int grow = m0 + row;
            const int y128 = grow >> 7;
            const int ld   = (y128 + 1) * 128;
            const int colg = n0 + col;
            if (colg < ld)
                Sz[(size_t)(y128 * (y128 + 1) / 2) * 16384
                   + (size_t)(grow & 127) * ld + colg] = f2bf(val * 0.03125f);
        })
    } else {
        EPILOGUE_VT(vt, m0, n0)
    }
}

// ---------------------------------------------------------------------------
// Legacy row softmax (G<4 path): in-place S -> P. grid (4096, G).
// ---------------------------------------------------------------------------
__global__ __launch_bounds__(256) void softmax_rows(unsigned short* __restrict__ sbuf)
{
    __shared__ float row[4096];
    __shared__ float red[4];
    const int q   = 4095 - (int)blockIdx.x;
    const int n   = q + 1;
    const int tid = threadIdx.x;
    const int y   = q >> 7;
    const int ld  = (y + 1) * 128;
    unsigned short* rp = sbuf + (size_t)blockIdx.y * SB_ELEMS
                       + (size_t)(y * (y + 1) / 2) * 16384
                       + (size_t)(q & 127) * ld;
    const int n8 = n & ~7;

    for (int i0 = tid * 8; i0 < n8; i0 += 2048) {
        const uint4 v = *(const uint4*)(rp + i0);
        *(float4*)&row[i0]     = make_float4(bflo(v.x), bfhi(v.x), bflo(v.y), bfhi(v.y));
        *(float4*)&row[i0 + 4] = make_float4(bflo(v.z), bfhi(v.z), bflo(v.w), bfhi(v.w));
    }
    for (int i = n8 + tid; i < n; i += 256)
        row[i] = bfu(rp[i]);
    __syncthreads();

    float m = -1e30f;
    for (int i = tid; i < n; i += 256) m = fmaxf(m, row[i]);
    #pragma unroll
    for (int off = 32; off >= 1; off >>= 1) m = fmaxf(m, __shfl_xor(m, off, 64));
    if ((tid & 63) == 0) red[tid >> 6] = m;
    __syncthreads();
    m = fmaxf(fmaxf(red[0], red[1]), fmaxf(red[2], red[3]));
    __syncthreads();

    float s = 0.f;
    for (int i = tid; i < n; i += 256) {
        const float e = __expf(row[i] - m);
        row[i] = e;
        s += e;
    }
    #pragma unroll
    for (int off = 32; off >= 1; off >>= 1) s += __shfl_xor(s, off, 64);
    if ((tid & 63) == 0) red[tid >> 6] = s;
    __syncthreads();
    s = red[0] + red[1] + red[2] + red[3];
    const float inv = 1.f / s;

    for (int i0 = tid * 8; i0 < n8; i0 += 2048) {
        const float4 f0 = *(const float4*)&row[i0];
        const float4 f1 = *(const float4*)&row[i0 + 4];
        uint4 pk;
        pk.x = pack2(f0.x * inv, f0.y * inv);
        pk.y = pack2(f0.z * inv, f0.w * inv);
        pk.z = pack2(f1.x * inv, f1.y * inv);
        pk.w = pack2(f1.z * inv, f1.w * inv);
        *(uint4*)(rp + i0) = pk;
    }
    for (int i = n8 + tid; i < ld; i += 256)
        rp[i] = (i < n) ? f2bf(row[i] * inv) : (unsigned short)0;
}

// ---------------------------------------------------------------------------
// Row stats (G=4 fused path): per-row (m, 1/s), IDENTICAL reduction order to
// softmax_rows => bit-identical (m, inv).  S left untouched.  grid (4096, G).
// ---------------------------------------------------------------------------
__global__ __launch_bounds__(256) void stats_rows(
    const unsigned short* __restrict__ sbuf, float2* __restrict__ stats)
{
    __shared__ float row[4096];
    __shared__ float red[4];
    const int q   = 4095 - (int)blockIdx.x;
    const int n   = q + 1;
    const int tid = threadIdx.x;
    const int y   = q >> 7;
    const int ld  = (y + 1) * 128;
    const unsigned short* rp = sbuf + (size_t)blockIdx.y * SB_ELEMS
                             + (size_t)(y * (y + 1) / 2) * 16384
                             + (size_t)(q & 127) * ld;
    const int n8 = n & ~7;

    for (int i0 = tid * 8; i0 < n8; i0 += 2048) {
        const uint4 v = *(const uint4*)(rp + i0);
        *(float4*)&row[i0]     = make_float4(bflo(v.x), bfhi(v.x), bflo(v.y), bfhi(v.y));
        *(float4*)&row[i0 + 4] = make_float4(bflo(v.z), bfhi(v.z), bflo(v.w), bfhi(v.w));
    }
    for (int i = n8 + tid; i < n; i += 256)
        row[i] = bfu(rp[i]);
    __syncthreads();

    float m = -1e30f;
    for (int i = tid; i < n; i += 256) m = fmaxf(m, row[i]);
    #pragma unroll
    for (int off = 32; off >= 1; off >>= 1) m = fmaxf(m, __shfl_xor(m, off, 64));
    if ((tid & 63) == 0) red[tid >> 6] = m;
    __syncthreads();
    m = fmaxf(fmaxf(red[0], red[1]), fmaxf(red[2], red[3]));
    __syncthreads();

    float s = 0.f;
    for (int i = tid; i < n; i += 256) s += __expf(row[i] - m);
    #pragma unroll
    for (int off = 32; off >= 1; off >>= 1) s += __shfl_xor(s, off, 64);
    if ((tid & 63) == 0) red[tid >> 6] = s;
    __syncthreads();
    s = red[0] + red[1] + red[2] + red[3];

    if (tid == 0)
        stats[(size_t)blockIdx.y * T_SEQ + q] = make_float2(m, 1.f / s);
}

// ---------------------------------------------------------------------------
// Legacy o_gemm (G<4): out = P.Vt^T.  grid (8, 32*G), 128x128.
// ---------------------------------------------------------------------------
__global__ __launch_bounds__(256) void o_gemm(
    const unsigned short* __restrict__ sbuf, const unsigned short* __restrict__ vt,
    float* __restrict__ out, int bbase)
{
    const int w  = blockIdx.y;
    const int gy = w & 31;
    const int z  = w >> 5;
    const int y  = (gy & 1) ? (gy >> 1) : (31 - (gy >> 1));
    const int b  = bbase + z;
    const int K_len = (y + 1) * 128;
    const unsigned short* A  = sbuf + (size_t)z * SB_ELEMS
                             + (size_t)(y * (y + 1) / 2) * 16384;
    const unsigned short* Bv = vt + (size_t)b * T_SEQ * DA;
    const int n0 = blockIdx.x * 128;

    GEMM_PROLOGUE_256
    k_loop_256(A, K_len, Bv, T_SEQ, 0, n0, K_len, Xs, Ws,
               tid, wm, wn, qq, r, swz, acc);

    float* outb = out + (size_t)b * T_SEQ * DA + (size_t)y * 128 * DA;
    EPILOGUE_LOOP({
        outb[(size_t)row * DA + (n0 + col)] = rintf(val * 1e4f) * 1e-4f;
    })
}

// ---------------------------------------------------------------------------
// Fused o_gemm (G=4): stages raw S, applies P = f2bf(exp(v-m)*inv) on the
// A-fragments in-register (identical rounding path to legacy softmax).
// grid (8, 128): s = w&31 (CU slot), rq = w>>5, i = s&7, z = s>>3,
//   y = {31-i, 16+i, 15-i, i}[rq]; per-CU K-units = 66 uniform.
// Causal mask (c > q -> 0) only in K-steps with k0+63 >= y*128.
// ---------------------------------------------------------------------------
__global__ __launch_bounds__(256) void o_gemm_fused(
    const unsigned short* __restrict__ sbuf, const unsigned short* __restrict__ vt,
    const float2* __restrict__ stats, float* __restrict__ out)
{
    const int w  = blockIdx.y;
    const int s  = w & 31;
    const int rq = w >> 5;
    const int ii = s & 7;
    const int z  = s >> 3;
    const int y  = (rq == 0) ? (31 - ii) : (rq == 1) ? (16 + ii)
                 : (rq == 2) ? (15 - ii) : ii;
    const int K_len = (y + 1) * 128;
    const unsigned short* A  = sbuf + (size_t)z * SB_ELEMS
                             + (size_t)(y * (y + 1) / 2) * 16384;
    const unsigned short* Bv = vt + (size_t)z * T_SEQ * DA;   // bbase=0 (G=4)
    const int n0 = blockIdx.x * 128;

    GEMM_PROLOGUE_256

    // per-lane row stats: rows y*128 + wm*64 + i*16 + r, i = 0..3
    float sm[4], si[4];
    int qrow[4];
    #pragma unroll
    for (int i = 0; i < 4; ++i) {
        qrow[i] = y * 128 + wm * 64 + i * 16 + r;
        const float2 st = stats[(size_t)z * T_SEQ + qrow[i]];
        sm[i] = st.x;
        si[i] = st.y;
    }

    // K-loop with fused exp on A fragments
    {
        const int srow = tid >> 3;
        const int scg  = STAGE_SCG;
        const unsigned short* ga = A + (size_t)srow * K_len + scg;
        const unsigned short* gb = Bv + (size_t)(n0 + srow) * T_SEQ + scg;
        unsigned short* la = Xs + tid * 8;
        unsigned short* lb = Ws + tid * 8;
        const size_t astep = (size_t)32 * K_len;
        const size_t bstep = (size_t)32 * T_SEQ;
        const int ybase = y * 128;

        for (int k0 = 0; k0 < K_len; k0 += 64) {
            const unsigned short* pa = ga;
            const unsigned short* pb = gb;
            #pragma unroll
            for (int p = 0; p < 4; ++p) {
                GLOAD_LDS16(pa, la + p * 2048);
                GLOAD_LDS16(pb, lb + p * 2048);
                pa += astep;
                pb += bstep;
            }
            ga += 64;
            gb += 64;
            __syncthreads();

            const bool tail = (k0 + 63 >= ybase);   // block-uniform
            #pragma unroll
            for (int h = 0; h < 2; ++h) {
                const int co = (h * 32) ^ swz;
                bf16x8 a[4], b[4];
                #pragma unroll
                for (int i = 0; i < 4; ++i) {
                    const bf16x8 raw =
                        *(const bf16x8*)&Xs[(wm * 64 + i * 16 + r) * 64 + co];
                    float p8[8];
                    #pragma unroll
                    for (int e = 0; e < 8; ++e)
                        p8[e] = __expf(bfu((unsigned short)raw[e]) - sm[i]) * si[i];
                    if (tail) {
                        const int cbase = k0 + h * 32 + qq * 8;
                        #pragma unroll
                        for (int e = 0; e < 8; ++e)
                            if (cbase + e > qrow[i]) p8[e] = 0.f;
                    }
                    unsigned u0 = pack2(p8[0], p8[1]);
                    unsigned u1 = pack2(p8[2], p8[3]);
                    unsigned u2 = pack2(p8[4], p8[5]);
                    unsigned u3 = pack2(p8[6], p8[7]);
                    bf16x8 pa8;
                    pa8[0] = (short)(u0 & 0xFFFF); pa8[1] = (short)(u0 >> 16);
                    pa8[2] = (short)(u1 & 0xFFFF); pa8[3] = (short)(u1 >> 16);
                    pa8[4] = (short)(u2 & 0xFFFF); pa8[5] = (short)(u2 >> 16);
                    pa8[6] = (short)(u3 & 0xFFFF); pa8[7] = (short)(u3 >> 16);
                    a[i] = pa8;
                }
                #pragma unroll
                for (int j = 0; j < 4; ++j)
                    b[j] = *(const bf16x8*)&Ws[(wn * 64 + j * 16 + r) * 64 + co];
                #pragma unroll
                for (int i = 0; i < 4; ++i)
                    #pragma unroll
                    for (int j = 0; j < 4; ++j)
                        acc[i][j] = __builtin_amdgcn_mfma_f32_16x16x32_bf16(
                            a[i], b[j], acc[i][j], 0, 0, 0);
            }
            __syncthreads();
        }
    }

    float* outb = out + (size_t)z * T_SEQ * DA + (size_t)y * 128 * DA;
    EPILOGUE_LOOP({
        outb[(size_t)row * DA + (n0 + col)] = rintf(val * 1e4f) * 1e-4f;
    })
}

// ---------------------------------------------------------------------------
extern "C" void kernel_launch(void* const* d_in, const int* in_sizes, int n_in,
                              void* d_out, int out_size, void* d_ws, size_t ws_size,
                              hipStream_t stream)
{
    const float* X  = (const float*)d_in[0];
    const float* Wq = (const float*)d_in[1];
    const float* Wk = (const float*)d_in[2];
    const float* Wv = (const float*)d_in[3];
    float* out = (float*)d_out;

    unsigned short* qb   = (unsigned short*)d_ws;          // [16384,1024]
    unsigned short* kb   = qb + (size_t)M_TOT * DA;
    unsigned short* vt   = kb + (size_t)M_TOT * DA;        // [4][1024][4096]
    unsigned short* sbuf = vt + (size_t)M_TOT * DA;        // G * SB_ELEMS

    // bf16 copies of X / W live in d_out (64 MB), dead until o_gemm writes.
    unsigned short* Xb = (unsigned short*)d_out;           // 32 MB
    unsigned short* Wb = Xb + (size_t)M_TOT * DA;          // 6 MB ([3*1024][1024])

    const size_t fixed = (size_t)3 * M_TOT * DA * 2;
    int G = 1;
    if (ws_size >= fixed + (size_t)4 * SB_ELEMS * 2) G = 4;
    else if (ws_size >= fixed + (size_t)2 * SB_ELEMS * 2) G = 2;

    to_bf16_all<<<9728, 256, 0, stream>>>(X, Wq, Wk, Wv, Xb, Wb);
    proj_qk<<<1024, 512, 0, stream>>>(Xb, Wb, qb, kb);
    if (G < 4)
        proj_v<<<512, 512, 0, stream>>>(Xb, Wb, vt);

    if (G == 4) {
        // single pass; qb/kb dead after s_gemm_v -> stats aliases qb
        float2* stats = (float2*)qb;
        s_gemm_v<<<dim3(400, 4), 512, 0, stream>>>(
            qb, kb, Xb, Wb, sbuf, vt, 0, 128);
        stats_rows<<<dim3(4096, 4), 256, 0, stream>>>(sbuf, stats);
        o_gemm_fused<<<dim3(8, 128), 256, 0, stream>>>(sbuf, vt, stats, out);
    } else {
        for (int b0 = 0; b0 < BATCH; b0 += G) {
            s_gemm_v<<<dim3(272, G), 512, 0, stream>>>(
                qb, kb, Xb, Wb, sbuf, vt, b0, 0);
            softmax_rows<<<dim3(4096, G), 256, 0, stream>>>(sbuf);
            o_gemm<<<dim3(8, 32 * G), 256, 0, stream>>>(sbuf, vt, out, b0);
        }
    }
}

// Round 9
// 446.625 us; speedup vs baseline: 1.2452x; 1.2452x over previous
//
#include <hip/hip_runtime.h>

// B=4, T=4096, D=A=1024.  All-MFMA bf16 pipeline, BK=64 async staging.
// R19: R14 restored verbatim (455us verified: 2-barrier BK=64 loops,
//   balanced grids, 0-conflict rotation swizzle) + o_gemm XCD-locality
//   remap: w = bx + 8*(by>>3), n0 = (by&7)*128  => the 8 column-blocks
//   sharing one P-panel land on ONE XCD (8 CUs) -> P hot in that L2
//   (was: n0 = bx -> 8 different XCDs, 8x P fetch; FETCH 287MB).
//   Balance preserved exactly: each CU still gets quad {31-i,16+i,15-i,i},
//   i = bx, 66 K-units; bijective; all 1024 blocks co-resident.
// Closed lines (counters): R11 8-phase (sync-bound @1 blk/CU), R15/16 BK32
//   dbuf (barrier drains prefetch), R17 128x256 (occupancy), R18 exp-fusion
//   (8x exp redundancy, VALU-bound 63%).  Law: this structure lives on
//   blocks/CU TLP; only cross-block locality + balance are safe levers.
// Rotation swizzle (verified 0 conflicts, 64-elem rows): logical granule g
//   of tile-row R stored at (g+R)&7; reads co=(h*32)^(((qq+r)&7)<<3);
//   staging source granule ((tid&7)-(tid>>3))&7; DMA dest linear lane*16B.
// Packed S: row-block y128 at elem offset y128(y128+1)/2*16384, ld (y128+1)*128.
// ws: Q 32MB | K 32MB | Vt 32MB | S G*17.3MB   (G from ws_size)
// d_out (64MB) doubles as Xb(32MB)+Wb(6MB) scratch during projection.

#define T_SEQ 4096
#define DA    1024
#define BATCH 4
#define M_TOT (BATCH * T_SEQ)            // 16384
#define SB_ELEMS 8650752                  // 528 tri-blocks * 16384 elems

typedef float  f32x4  __attribute__((ext_vector_type(4)));
typedef short  bf16x8 __attribute__((ext_vector_type(8)));

static __device__ __forceinline__ unsigned short f2bf(float f) {
    unsigned u = __builtin_bit_cast(unsigned, f);
    u += 0x7FFFu + ((u >> 16) & 1u);      // RNE
    return (unsigned short)(u >> 16);
}
static __device__ __forceinline__ unsigned pack2(float a, float b) {
    return (unsigned)f2bf(a) | ((unsigned)f2bf(b) << 16);
}
static __device__ __forceinline__ float bflo(unsigned u) {
    return __builtin_bit_cast(float, u << 16);
}
static __device__ __forceinline__ float bfhi(unsigned u) {
    return __builtin_bit_cast(float, u & 0xFFFF0000u);
}

// async global->LDS, 16 B per lane; LDS dest = wave-uniform base + lane*16
#define GLOAD_LDS16(g, l)                                                   \
    __builtin_amdgcn_global_load_lds(                                       \
        (const __attribute__((address_space(1))) void*)(g),                 \
        (__attribute__((address_space(3))) void*)(l), 16, 0, 0)

// source-granule pre-permute for the rotation swizzle: LDS slot
// (row = tid>>3 (+chunk), granule = tid&7) holds global granule
// ((tid&7) - (tid>>3)) & 7  of that row.
#define STAGE_SCG  (((((tid & 7) - (tid >> 3)) & 7)) * 8)

// ---------------------------------------------------------------------------
// MFMA core (shared): per wave 64x64 out of Xs rows [wm*64,+64), Ws [wn*64,+64)
// ---------------------------------------------------------------------------
static __device__ __forceinline__ void mfma_step(
    const unsigned short* __restrict__ Xs, const unsigned short* __restrict__ Ws,
    int wm, int wn, int qq, int r, int swz, f32x4 acc[4][4])
{
    #pragma unroll
    for (int h = 0; h < 2; ++h) {
        const int co = (h * 32) ^ swz;            // qq folded into swz
        bf16x8 a[4], b[4];
        #pragma unroll
        for (int i = 0; i < 4; ++i)
            a[i] = *(const bf16x8*)&Xs[(wm * 64 + i * 16 + r) * 64 + co];
        #pragma unroll
        for (int j = 0; j < 4; ++j)
            b[j] = *(const bf16x8*)&Ws[(wn * 64 + j * 16 + r) * 64 + co];
        #pragma unroll
        for (int i = 0; i < 4; ++i)
            #pragma unroll
            for (int j = 0; j < 4; ++j)
                acc[i][j] = __builtin_amdgcn_mfma_f32_16x16x32_bf16(
                    a[i], b[j], acc[i][j], 0, 0, 0);
    }
}

// ---------------------------------------------------------------------------
// 256-thread K-loop: 128x64 A + 128x64 B tiles (o_gemm).
// ---------------------------------------------------------------------------
static __device__ __forceinline__ void k_loop_256(
    const unsigned short* __restrict__ A, int lda,
    const unsigned short* __restrict__ B, int ldb,
    int m0, int n0, int K,
    unsigned short* __restrict__ Xs, unsigned short* __restrict__ Ws,
    int tid, int wm, int wn, int qq, int r, int swz, f32x4 acc[4][4])
{
    const int srow = tid >> 3;                              // 0..31
    const int scg  = STAGE_SCG;
    const unsigned short* ga = A + (size_t)(m0 + srow) * lda + scg;
    const unsigned short* gb = B + (size_t)(n0 + srow) * ldb + scg;
    unsigned short* la = Xs + tid * 8;
    unsigned short* lb = Ws + tid * 8;
    const size_t astep = (size_t)32 * lda;
    const size_t bstep = (size_t)32 * ldb;

    for (int k0 = 0; k0 < K; k0 += 64) {
        const unsigned short* pa = ga;
        const unsigned short* pb = gb;
        #pragma unroll
        for (int p = 0; p < 4; ++p) {
            GLOAD_LDS16(pa, la + p * 2048);
            GLOAD_LDS16(pb, lb + p * 2048);
            pa += astep;
            pb += bstep;
        }
        ga += 64;
        gb += 64;
        __syncthreads();
        mfma_step(Xs, Ws, wm, wn, qq, r, swz, acc);
        __syncthreads();
    }
}

// ---------------------------------------------------------------------------
// 512-thread K-loop: 256x64 A + 128x64 B tiles (proj/s_gemm_v).
// ---------------------------------------------------------------------------
static __device__ __forceinline__ void k_loop_512(
    const unsigned short* __restrict__ A, int lda,
    const unsigned short* __restrict__ B, int ldb,
    int m0, int n0, int K,
    unsigned short* __restrict__ Xs, unsigned short* __restrict__ Ws,
    int tid, int wm, int wn, int qq, int r, int swz, f32x4 acc[4][4])
{
    const int srow = tid >> 3;                              // 0..63
    const int scg  = STAGE_SCG;
    const unsigned short* ga = A + (size_t)(m0 + srow) * lda + scg;
    const unsigned short* gb = B + (size_t)(n0 + srow) * ldb + scg;
    unsigned short* la = Xs + tid * 8;
    unsigned short* lb = Ws + tid * 8;
    const size_t astep = (size_t)64 * lda;
    const size_t bstep = (size_t)64 * ldb;

    for (int k0 = 0; k0 < K; k0 += 64) {
        const unsigned short* pa = ga;
        #pragma unroll
        for (int p = 0; p < 4; ++p) {           // A: 4 x 64 rows = 256
            GLOAD_LDS16(pa, la + p * 4096);
            pa += astep;
        }
        const unsigned short* pb = gb;
        #pragma unroll
        for (int p = 0; p < 2; ++p) {           // B: 2 x 64 rows = 128
            GLOAD_LDS16(pb, lb + p * 4096);
            pb += bstep;
        }
        ga += 64;
        gb += 64;
        __syncthreads();
        mfma_step(Xs, Ws, wm, wn, qq, r, swz, acc);
        __syncthreads();
    }
}

#define GEMM_VARS                                                            \
    const int tid  = threadIdx.x;                                            \
    const int wave = tid >> 6;                                               \
    const int lane = tid & 63;                                               \
    const int wm   = wave >> 1;                                              \
    const int wn   = wave & 1;                                               \
    const int qq   = lane >> 4;                                              \
    const int r    = lane & 15;                                              \
    const int swz  = ((qq + r) & 7) << 3;                                    \
    f32x4 acc[4][4];                                                         \
    _Pragma("unroll")                                                        \
    for (int i = 0; i < 4; ++i)                                              \
        _Pragma("unroll")                                                    \
        for (int j = 0; j < 4; ++j)                                          \
            acc[i][j] = f32x4{0.f, 0.f, 0.f, 0.f};

#define GEMM_PROLOGUE_256                                                    \
    __shared__ unsigned short Xs[8192];                                      \
    __shared__ unsigned short Ws[8192];                                      \
    GEMM_VARS

#define GEMM_PROLOGUE_512                                                    \
    __shared__ unsigned short Xs[16384];                                     \
    __shared__ unsigned short Ws[8192];                                      \
    GEMM_VARS

// C/D layout: col = lane&15, row = (lane>>4)*4 + reg   (row within wave tile)
#define EPILOGUE_LOOP(BODY)                                                  \
    _Pragma("unroll")                                                        \
    for (int i = 0; i < 4; ++i)                                              \
        _Pragma("unroll")                                                    \
        for (int j = 0; j < 4; ++j)                                          \
            _Pragma("unroll")                                                \
            for (int rr = 0; rr < 4; ++rr) {                                 \
                const int row = wm * 64 + i * 16 + qq * 4 + rr;              \
                const int col = wn * 64 + j * 16 + r;                        \
                const float val = acc[i][j][rr];                             \
                BODY                                                         \
            }

// transposed V epilogue: rows rg0..rg0+3 are consecutive t -> one ushort4
#define EPILOGUE_VT(VT, M0, NC)                                              \
    _Pragma("unroll")                                                        \
    for (int i = 0; i < 4; ++i)                                              \
        _Pragma("unroll")                                                    \
        for (int j = 0; j < 4; ++j) {                                        \
            const int rg0 = (M0) + wm * 64 + i * 16 + qq * 4;                \
            const int col = wn * 64 + j * 16 + r;                            \
            const int bb  = rg0 >> 12;                                       \
            const int tt  = rg0 & 4095;                                      \
            ushort4 pkv;                                                     \
            pkv.x = f2bf(acc[i][j][0]); pkv.y = f2bf(acc[i][j][1]);          \
            pkv.z = f2bf(acc[i][j][2]); pkv.w = f2bf(acc[i][j][3]);          \
            *(ushort4*)&(VT)[((size_t)bb << 22) +                            \
                             (size_t)((NC) + col) * 4096 + tt] = pkv;        \
        }

// ---------------------------------------------------------------------------
// fp32 -> bf16 conversion. Blocks 0..8191: X. Blocks 8192..9727: Wq|Wk|Wv.
// ---------------------------------------------------------------------------
__global__ __launch_bounds__(256) void to_bf16_all(
    const float* __restrict__ X, const float* __restrict__ Wq,
    const float* __restrict__ Wk, const float* __restrict__ Wv,
    unsigned short* __restrict__ Xb, unsigned short* __restrict__ Wb)
{
    const int bx = blockIdx.x;
    const float* src;
    unsigned short* dst;
    size_t off;
    if (bx < 8192) {
        src = X; dst = Xb; off = (size_t)bx * 2048;
    } else {
        const int s   = bx - 8192;
        const int seg = s >> 9;
        src = (seg == 0) ? Wq : (seg == 1) ? Wk : Wv;
        dst = Wb + (size_t)seg * (DA * DA);
        off = (size_t)(s & 511) * 2048;
    }
    const size_t i = off + (size_t)threadIdx.x * 8;
    const float4 v0 = *(const float4*)(src + i);
    const float4 v1 = *(const float4*)(src + i + 4);
    uint4 pk;
    pk.x = pack2(v0.x, v0.y); pk.y = pack2(v0.z, v0.w);
    pk.z = pack2(v1.x, v1.y); pk.w = pack2(v1.z, v1.w);
    *(uint4*)(dst + i) = pk;
}

// ---------------------------------------------------------------------------
// Q,K projections, 256x128 tiles. Wb = [3*1024][1024]. 1024 blocks,
// XCD-swizzled: xcd owns mt band [xcd*8, xcd*8+8), n fastest.
// ---------------------------------------------------------------------------
__global__ __launch_bounds__(512) void proj_qk(
    const unsigned short* __restrict__ Xb, const unsigned short* __restrict__ Wb,
    unsigned short* __restrict__ qb, unsigned short* __restrict__ kb)
{
    const int li   = blockIdx.x;
    const int xcd  = li & 7;
    const int slot = li >> 3;            // 0..127
    const int mt   = xcd * 8 + (slot >> 4);
    const int nt   = slot & 15;          // 0..15 across Wq|Wk
    const int m0   = mt * 256;

    GEMM_PROLOGUE_512
    k_loop_512(Xb, DA, Wb, DA, m0, nt * 128, DA, Xs, Ws,
               tid, wm, wn, qq, r, swz, acc);

    unsigned short* Y = (nt >> 3) ? kb : qb;
    const int nc = (nt & 7) * 128;
    EPILOGUE_LOOP({
        Y[(size_t)(m0 + row) * DA + (nc + col)] = f2bf(val);
    })
}

// ---------------------------------------------------------------------------
// Fallback V projection (only if workspace forces G<4). 512 blocks, 256x128.
// ---------------------------------------------------------------------------
__global__ __launch_bounds__(512) void proj_v(
    const unsigned short* __restrict__ Xb, const unsigned short* __restrict__ Wb,
    unsigned short* __restrict__ vt)
{
    const int li = blockIdx.x;           // 0..511
    const int m0 = (li >> 3) * 256;
    const int n0 = (li & 7) * 128;
    GEMM_PROLOGUE_512
    k_loop_512(Xb, DA, Wb + (size_t)2048 * DA, DA, m0, n0, DA, Xs, Ws,
               tid, wm, wn, qq, r, swz, acc);
    EPILOGUE_VT(vt, m0, n0)
}

// ---------------------------------------------------------------------------
// S = Q.K^T / 32 (lower-tri, packed) with V tiles on dead upper slots.
// Flat active-only grid (272 + vPerZ, G), 512 threads, 256x128 tiles.
// t < 272: S tile; triangular decode yr(yr+1) <= t < (yr+1)(yr+2),
//   x = t - yr(yr+1).  Rows span packed blocks 2yr, 2yr+1 (different ld)
//   -> per-element y128/ld; col guard drops dead half of boundary tile.
// t >= 272: V tile vid = bz*vPerZ + (t-272).
// ---------------------------------------------------------------------------
__global__ __launch_bounds__(512) void s_gemm_v(
    const unsigned short* __restrict__ qb, const unsigned short* __restrict__ kb,
    const unsigned short* __restrict__ Xb, const unsigned short* __restrict__ Wb,
    unsigned short* __restrict__ sbuf, unsigned short* __restrict__ vt,
    int bbase, int vPerZ)
{
    const int t  = blockIdx.x;
    const int bz = blockIdx.y;
    const bool isS = (t < 272);

    const unsigned short *Am, *Bm;
    int m0, n0;
    if (isS) {
        int yr = (int)((__fsqrt_rn(4.f * (float)t + 1.f) - 1.f) * 0.5f);
        while ((yr + 1) * (yr + 2) <= t) ++yr;      // exact fixup
        while (yr * (yr + 1) > t) --yr;
        const int x = t - yr * (yr + 1);
        const int b = bbase + bz;
        Am = qb + (size_t)b * T_SEQ * DA;
        Bm = kb + (size_t)b * T_SEQ * DA;
        m0 = yr * 256;
        n0 = x * 128;
    } else {
        const int vid = bz * vPerZ + (t - 272);      // 0..511
        Am = Xb;
        Bm = Wb + (size_t)2048 * DA;
        m0 = (vid >> 3) * 256;
        n0 = (vid & 7) * 128;
    }

    GEMM_PROLOGUE_512
    k_loop_512(Am, DA, Bm, DA, m0, n0, DA, Xs, Ws,
               tid, wm, wn, qq, r, swz, acc);

    if (isS) {
        unsigned short* Sz = sbuf + (size_t)bz * SB_ELEMS;
        EPILOGUE_LOOP({
            const int grow = m0 + row;
            const int y128 = grow >> 7;
            const int ld   = (y128 + 1) * 128;
            const int colg = n0 + col;
            if (colg < ld)
                Sz[(size_t)(y128 * (y128 + 1) / 2) * 16384
                   + (size_t)(grow & 127) * ld + colg] = f2bf(val * 0.03125f);
        })
    } else {
        EPILOGUE_VT(vt, m0, n0)
    }
}

// ---------------------------------------------------------------------------
// Row softmax on packed S. grid (4096, G); big rows first.
// ---------------------------------------------------------------------------
__global__ __launch_bounds__(256) void softmax_rows(unsigned short* __restrict__ sbuf)
{
    __shared__ float row[4096];
    __shared__ float red[4];
    const int q   = 4095 - (int)blockIdx.x;
    const int n   = q + 1;
    const int tid = threadIdx.x;
    const int y   = q >> 7;
    const int ld  = (y + 1) * 128;
    unsigned short* rp = sbuf + (size_t)blockIdx.y * SB_ELEMS
                       + (size_t)(y * (y + 1) / 2) * 16384
                       + (size_t)(q & 127) * ld;
    const int n8 = n & ~7;

    for (int i0 = tid * 8; i0 < n8; i0 += 2048) {
        const uint4 v = *(const uint4*)(rp + i0);
        *(float4*)&row[i0]     = make_float4(bflo(v.x), bfhi(v.x), bflo(v.y), bfhi(v.y));
        *(float4*)&row[i0 + 4] = make_float4(bflo(v.z), bfhi(v.z), bflo(v.w), bfhi(v.w));
    }
    for (int i = n8 + tid; i < n; i += 256)
        row[i] = __builtin_bit_cast(float, (unsigned)rp[i] << 16);
    __syncthreads();

    float m = -1e30f;
    for (int i = tid; i < n; i += 256) m = fmaxf(m, row[i]);
    #pragma unroll
    for (int off = 32; off >= 1; off >>= 1) m = fmaxf(m, __shfl_xor(m, off, 64));
    if ((tid & 63) == 0) red[tid >> 6] = m;
    __syncthreads();
    m = fmaxf(fmaxf(red[0], red[1]), fmaxf(red[2], red[3]));
    __syncthreads();

    float s = 0.f;
    for (int i = tid; i < n; i += 256) {
        const float e = __expf(row[i] - m);
        row[i] = e;
        s += e;
    }
    #pragma unroll
    for (int off = 32; off >= 1; off >>= 1) s += __shfl_xor(s, off, 64);
    if ((tid & 63) == 0) red[tid >> 6] = s;
    __syncthreads();
    s = red[0] + red[1] + red[2] + red[3];
    const float inv = 1.f / s;

    for (int i0 = tid * 8; i0 < n8; i0 += 2048) {
        const float4 f0 = *(const float4*)&row[i0];
        const float4 f1 = *(const float4*)&row[i0 + 4];
        uint4 pk;
        pk.x = pack2(f0.x * inv, f0.y * inv);
        pk.y = pack2(f0.z * inv, f0.w * inv);
        pk.z = pack2(f1.x * inv, f1.y * inv);
        pk.w = pack2(f1.z * inv, f1.w * inv);
        *(uint4*)(rp + i0) = pk;
    }
    for (int i = n8 + tid; i < ld; i += 256)
        rp[i] = (i < n) ? f2bf(row[i] * inv) : (unsigned short)0;
}

// ---------------------------------------------------------------------------
// out = P.Vt^T, K = (y+1)*128. grid (8, 32*G), 256 threads, 128x128.
// G==4 (gridDim.y==128): XCD-locality mapping -- w = bx + 8*(by>>3),
//   n0 = (by&7)*128.  bid&7 = w&7 => the 8 n0-siblings of one w (sharing the
//   P panel) land on ONE XCD, 8 distinct CUs (bid>>3 consecutive) => P hot
//   in that XCD's L2.  Each CU hosts the full quad {31-i,16+i,15-i,i},
//   i = bx => 66 K-units/CU uniform.  All 1024 blocks co-resident (5/CU cap).
// G<4 fallback: legacy interleave.
// ---------------------------------------------------------------------------
__global__ __launch_bounds__(256) void o_gemm(
    const unsigned short* __restrict__ sbuf, const unsigned short* __restrict__ vt,
    float* __restrict__ out, int bbase)
{
    const int by = blockIdx.y;
    int y, z, n0;
    if (gridDim.y == 128) {
        const int w  = blockIdx.x + 8 * (by >> 3);   // 0..127 slot-major
        n0 = (by & 7) * 128;
        const int s  = w & 31;
        const int rq = w >> 5;
        const int i  = s & 7;
        z = s >> 3;
        y = (rq == 0) ? (31 - i) : (rq == 1) ? (16 + i)
          : (rq == 2) ? (15 - i) : i;
    } else {
        n0 = blockIdx.x * 128;
        const int gy = by & 31;
        z = by >> 5;
        y = (gy & 1) ? (gy >> 1) : (31 - (gy >> 1));
    }
    const int b  = bbase + z;
    const int K_len = (y + 1) * 128;
    const unsigned short* A  = sbuf + (size_t)z * SB_ELEMS
                             + (size_t)(y * (y + 1) / 2) * 16384;
    const unsigned short* Bv = vt + (size_t)b * T_SEQ * DA;   // [1024][4096]

    GEMM_PROLOGUE_256
    k_loop_256(A, K_len, Bv, T_SEQ, 0, n0, K_len, Xs, Ws,
               tid, wm, wn, qq, r, swz, acc);

    float* outb = out + (size_t)b * T_SEQ * DA + (size_t)y * 128 * DA;
    EPILOGUE_LOOP({
        outb[(size_t)row * DA + (n0 + col)] = rintf(val * 1e4f) * 1e-4f;
    })
}

// ---------------------------------------------------------------------------
extern "C" void kernel_launch(void* const* d_in, const int* in_sizes, int n_in,
                              void* d_out, int out_size, void* d_ws, size_t ws_size,
                              hipStream_t stream)
{
    const float* X  = (const float*)d_in[0];
    const float* Wq = (const float*)d_in[1];
    const float* Wk = (const float*)d_in[2];
    const float* Wv = (const float*)d_in[3];
    float* out = (float*)d_out;

    unsigned short* qb   = (unsigned short*)d_ws;          // [16384,1024]
    unsigned short* kb   = qb + (size_t)M_TOT * DA;
    unsigned short* vt   = kb + (size_t)M_TOT * DA;        // [4][1024][4096]
    unsigned short* sbuf = vt + (size_t)M_TOT * DA;        // G * SB_ELEMS

    // bf16 copies of X / W live in d_out (64 MB), dead until o_gemm writes.
    unsigned short* Xb = (unsigned short*)d_out;           // 32 MB
    unsigned short* Wb = Xb + (size_t)M_TOT * DA;          // 6 MB ([3*1024][1024])

    const size_t fixed = (size_t)3 * M_TOT * DA * 2;
    int G = 1;
    if (ws_size >= fixed + (size_t)4 * SB_ELEMS * 2) G = 4;
    else if (ws_size >= fixed + (size_t)2 * SB_ELEMS * 2) G = 2;

    to_bf16_all<<<9728, 256, 0, stream>>>(X, Wq, Wk, Wv, Xb, Wb);
    proj_qk<<<1024, 512, 0, stream>>>(Xb, Wb, qb, kb);
    if (G < 4)
        proj_v<<<512, 512, 0, stream>>>(Xb, Wb, vt);

    for (int b0 = 0; b0 < BATCH; b0 += G) {
        const int vPerZ = (G == 4) ? 128 : 0;   // V fused only in the G=4 path
        s_gemm_v<<<dim3(272 + vPerZ, G), 512, 0, stream>>>(
            qb, kb, Xb, Wb, sbuf, vt, b0, vPerZ);
        softmax_rows<<<dim3(4096, G), 256, 0, stream>>>(sbuf);
        o_gemm<<<dim3(8, 32 * G), 256, 0, stream>>>(sbuf, vt, out, b0);
    }
}

// Round 10
// 439.994 us; speedup vs baseline: 1.2639x; 1.0151x over previous
//
#include <hip/hip_runtime.h>

// B=4, T=4096, D=A=1024.  All-MFMA bf16 pipeline, BK=64 async staging.
// R20: R19 (446.6us verified) + two dispatch-topology changes, zero
//   inner-loop changes:
//   1) V-projection tiles moved from s_gemm_v into proj_qkv:
//      proj_qkv = 1024 QK + 512 V = 1536 blocks = EXACTLY 2.0 generations
//      at 3 blocks/CU (768 slots); s_gemm = 1088 = 1.42 rounds (was 1600 =
//      2.08 -> 3-generation quantization).  Combined generations 5 -> 4.
//      All tasks uniform K=1024; V code = verified proj_v path.
//   2) s_gemm XCD chunking (same lever as R19's o_gemm win): flat bid,
//      u = (bid&7)*C + (bid>>3), C = 34*G -> each XCD owns a contiguous
//      task chunk; consecutive tasks share the 512KB Q-panel in that
//      XCD's L2 (was round-robin = 8-XCD panel thrash, FETCH 336MB).
//      V-part of proj_qkv likewise: xcd = vi&7, w = vi>>3,
//      mv = xcd*8 + (w>>3), n0 = (w&7)*128 -> 8 consecutive blocks share
//      one Xb panel, co-located with that XCD's QK band.
// Closed lines (counters): R11 8-phase, R15/16 BK32 dbuf, R17 128x256,
//   R18 exp-fusion.  Law: blocks/CU TLP is the engine; only cross-block
//   locality/balance/packing are safe levers.
// Rotation swizzle (verified 0 conflicts, 64-elem rows): logical granule g
//   of tile-row R stored at (g+R)&7; reads co=(h*32)^(((qq+r)&7)<<3);
//   staging source granule ((tid&7)-(tid>>3))&7; DMA dest linear lane*16B.
// Packed S: row-block y128 at elem offset y128(y128+1)/2*16384, ld (y128+1)*128.
// ws: Q 32MB | K 32MB | Vt 32MB | S G*17.3MB   (G from ws_size)
// d_out (64MB) doubles as Xb(32MB)+Wb(6MB) scratch; dead once proj_qkv ends.

#define T_SEQ 4096
#define DA    1024
#define BATCH 4
#define M_TOT (BATCH * T_SEQ)            // 16384
#define SB_ELEMS 8650752                  // 528 tri-blocks * 16384 elems

typedef float  f32x4  __attribute__((ext_vector_type(4)));
typedef short  bf16x8 __attribute__((ext_vector_type(8)));

static __device__ __forceinline__ unsigned short f2bf(float f) {
    unsigned u = __builtin_bit_cast(unsigned, f);
    u += 0x7FFFu + ((u >> 16) & 1u);      // RNE
    return (unsigned short)(u >> 16);
}
static __device__ __forceinline__ unsigned pack2(float a, float b) {
    return (unsigned)f2bf(a) | ((unsigned)f2bf(b) << 16);
}
static __device__ __forceinline__ float bflo(unsigned u) {
    return __builtin_bit_cast(float, u << 16);
}
static __device__ __forceinline__ float bfhi(unsigned u) {
    return __builtin_bit_cast(float, u & 0xFFFF0000u);
}

// async global->LDS, 16 B per lane; LDS dest = wave-uniform base + lane*16
#define GLOAD_LDS16(g, l)                                                   \
    __builtin_amdgcn_global_load_lds(                                       \
        (const __attribute__((address_space(1))) void*)(g),                 \
        (__attribute__((address_space(3))) void*)(l), 16, 0, 0)

// source-granule pre-permute for the rotation swizzle: LDS slot
// (row = tid>>3 (+chunk), granule = tid&7) holds global granule
// ((tid&7) - (tid>>3)) & 7  of that row.
#define STAGE_SCG  (((((tid & 7) - (tid >> 3)) & 7)) * 8)

// ---------------------------------------------------------------------------
// MFMA core (shared): per wave 64x64 out of Xs rows [wm*64,+64), Ws [wn*64,+64)
// ---------------------------------------------------------------------------
static __device__ __forceinline__ void mfma_step(
    const unsigned short* __restrict__ Xs, const unsigned short* __restrict__ Ws,
    int wm, int wn, int qq, int r, int swz, f32x4 acc[4][4])
{
    #pragma unroll
    for (int h = 0; h < 2; ++h) {
        const int co = (h * 32) ^ swz;            // qq folded into swz
        bf16x8 a[4], b[4];
        #pragma unroll
        for (int i = 0; i < 4; ++i)
            a[i] = *(const bf16x8*)&Xs[(wm * 64 + i * 16 + r) * 64 + co];
        #pragma unroll
        for (int j = 0; j < 4; ++j)
            b[j] = *(const bf16x8*)&Ws[(wn * 64 + j * 16 + r) * 64 + co];
        #pragma unroll
        for (int i = 0; i < 4; ++i)
            #pragma unroll
            for (int j = 0; j < 4; ++j)
                acc[i][j] = __builtin_amdgcn_mfma_f32_16x16x32_bf16(
                    a[i], b[j], acc[i][j], 0, 0, 0);
    }
}

// ---------------------------------------------------------------------------
// 256-thread K-loop: 128x64 A + 128x64 B tiles (o_gemm).
// ---------------------------------------------------------------------------
static __device__ __forceinline__ void k_loop_256(
    const unsigned short* __restrict__ A, int lda,
    const unsigned short* __restrict__ B, int ldb,
    int m0, int n0, int K,
    unsigned short* __restrict__ Xs, unsigned short* __restrict__ Ws,
    int tid, int wm, int wn, int qq, int r, int swz, f32x4 acc[4][4])
{
    const int srow = tid >> 3;                              // 0..31
    const int scg  = STAGE_SCG;
    const unsigned short* ga = A + (size_t)(m0 + srow) * lda + scg;
    const unsigned short* gb = B + (size_t)(n0 + srow) * ldb + scg;
    unsigned short* la = Xs + tid * 8;
    unsigned short* lb = Ws + tid * 8;
    const size_t astep = (size_t)32 * lda;
    const size_t bstep = (size_t)32 * ldb;

    for (int k0 = 0; k0 < K; k0 += 64) {
        const unsigned short* pa = ga;
        const unsigned short* pb = gb;
        #pragma unroll
        for (int p = 0; p < 4; ++p) {
            GLOAD_LDS16(pa, la + p * 2048);
            GLOAD_LDS16(pb, lb + p * 2048);
            pa += astep;
            pb += bstep;
        }
        ga += 64;
        gb += 64;
        __syncthreads();
        mfma_step(Xs, Ws, wm, wn, qq, r, swz, acc);
        __syncthreads();
    }
}

// ---------------------------------------------------------------------------
// 512-thread K-loop: 256x64 A + 128x64 B tiles (proj/s_gemm).
// ---------------------------------------------------------------------------
static __device__ __forceinline__ void k_loop_512(
    const unsigned short* __restrict__ A, int lda,
    const unsigned short* __restrict__ B, int ldb,
    int m0, int n0, int K,
    unsigned short* __restrict__ Xs, unsigned short* __restrict__ Ws,
    int tid, int wm, int wn, int qq, int r, int swz, f32x4 acc[4][4])
{
    const int srow = tid >> 3;                              // 0..63
    const int scg  = STAGE_SCG;
    const unsigned short* ga = A + (size_t)(m0 + srow) * lda + scg;
    const unsigned short* gb = B + (size_t)(n0 + srow) * ldb + scg;
    unsigned short* la = Xs + tid * 8;
    unsigned short* lb = Ws + tid * 8;
    const size_t astep = (size_t)64 * lda;
    const size_t bstep = (size_t)64 * ldb;

    for (int k0 = 0; k0 < K; k0 += 64) {
        const unsigned short* pa = ga;
        #pragma unroll
        for (int p = 0; p < 4; ++p) {           // A: 4 x 64 rows = 256
            GLOAD_LDS16(pa, la + p * 4096);
            pa += astep;
        }
        const unsigned short* pb = gb;
        #pragma unroll
        for (int p = 0; p < 2; ++p) {           // B: 2 x 64 rows = 128
            GLOAD_LDS16(pb, lb + p * 4096);
            pb += bstep;
        }
        ga += 64;
        gb += 64;
        __syncthreads();
        mfma_step(Xs, Ws, wm, wn, qq, r, swz, acc);
        __syncthreads();
    }
}

#define GEMM_VARS                                                            \
    const int tid  = threadIdx.x;                                            \
    const int wave = tid >> 6;                                               \
    const int lane = tid & 63;                                               \
    const int wm   = wave >> 1;                                              \
    const int wn   = wave & 1;                                               \
    const int qq   = lane >> 4;                                              \
    const int r    = lane & 15;                                              \
    const int swz  = ((qq + r) & 7) << 3;                                    \
    f32x4 acc[4][4];                                                         \
    _Pragma("unroll")                                                        \
    for (int i = 0; i < 4; ++i)                                              \
        _Pragma("unroll")                                                    \
        for (int j = 0; j < 4; ++j)                                          \
            acc[i][j] = f32x4{0.f, 0.f, 0.f, 0.f};

#define GEMM_PROLOGUE_256                                                    \
    __shared__ unsigned short Xs[8192];                                      \
    __shared__ unsigned short Ws[8192];                                      \
    GEMM_VARS

#define GEMM_PROLOGUE_512                                                    \
    __shared__ unsigned short Xs[16384];                                     \
    __shared__ unsigned short Ws[8192];                                      \
    GEMM_VARS

// C/D layout: col = lane&15, row = (lane>>4)*4 + reg   (row within wave tile)
#define EPILOGUE_LOOP(BODY)                                                  \
    _Pragma("unroll")                                                        \
    for (int i = 0; i < 4; ++i)                                              \
        _Pragma("unroll")                                                    \
        for (int j = 0; j < 4; ++j)                                          \
            _Pragma("unroll")                                                \
            for (int rr = 0; rr < 4; ++rr) {                                 \
                const int row = wm * 64 + i * 16 + qq * 4 + rr;              \
                const int col = wn * 64 + j * 16 + r;                        \
                const float val = acc[i][j][rr];                             \
                BODY                                                         \
            }

// transposed V epilogue: rows rg0..rg0+3 are consecutive t -> one ushort4
#define EPILOGUE_VT(VT, M0, NC)                                              \
    _Pragma("unroll")                                                        \
    for (int i = 0; i < 4; ++i)                                              \
        _Pragma("unroll")                                                    \
        for (int j = 0; j < 4; ++j) {                                        \
            const int rg0 = (M0) + wm * 64 + i * 16 + qq * 4;                \
            const int col = wn * 64 + j * 16 + r;                            \
            const int bb  = rg0 >> 12;                                       \
            const int tt  = rg0 & 4095;                                      \
            ushort4 pkv;                                                     \
            pkv.x = f2bf(acc[i][j][0]); pkv.y = f2bf(acc[i][j][1]);          \
            pkv.z = f2bf(acc[i][j][2]); pkv.w = f2bf(acc[i][j][3]);          \
            *(ushort4*)&(VT)[((size_t)bb << 22) +                            \
                             (size_t)((NC) + col) * 4096 + tt] = pkv;        \
        }

// ---------------------------------------------------------------------------
// fp32 -> bf16 conversion. Blocks 0..8191: X. Blocks 8192..9727: Wq|Wk|Wv.
// ---------------------------------------------------------------------------
__global__ __launch_bounds__(256) void to_bf16_all(
    const float* __restrict__ X, const float* __restrict__ Wq,
    const float* __restrict__ Wk, const float* __restrict__ Wv,
    unsigned short* __restrict__ Xb, unsigned short* __restrict__ Wb)
{
    const int bx = blockIdx.x;
    const float* src;
    unsigned short* dst;
    size_t off;
    if (bx < 8192) {
        src = X; dst = Xb; off = (size_t)bx * 2048;
    } else {
        const int s   = bx - 8192;
        const int seg = s >> 9;
        src = (seg == 0) ? Wq : (seg == 1) ? Wk : Wv;
        dst = Wb + (size_t)seg * (DA * DA);
        off = (size_t)(s & 511) * 2048;
    }
    const size_t i = off + (size_t)threadIdx.x * 8;
    const float4 v0 = *(const float4*)(src + i);
    const float4 v1 = *(const float4*)(src + i + 4);
    uint4 pk;
    pk.x = pack2(v0.x, v0.y); pk.y = pack2(v0.z, v0.w);
    pk.z = pack2(v1.x, v1.y); pk.w = pack2(v1.z, v1.w);
    *(uint4*)(dst + i) = pk;
}

// ---------------------------------------------------------------------------
// Q,K,V projections, 256x128 tiles, 1536 blocks = exactly 2 generations.
// li < 1024: QK -- xcd = li&7 owns mt band [xcd*8,+8), nt = slot&15 fastest
//   (16 consecutive slots share the 512KB Xb panel in-XCD).
// li >= 1024: V -- vi = li-1024; xcd = vi&7, w = vi>>3;
//   mv = xcd*8 + (w>>3), n0 = (w&7)*128 (8 consecutive blocks share one Xb
//   panel, co-located with that XCD's QK band).
// ---------------------------------------------------------------------------
__global__ __launch_bounds__(512) void proj_qkv(
    const unsigned short* __restrict__ Xb, const unsigned short* __restrict__ Wb,
    unsigned short* __restrict__ qb, unsigned short* __restrict__ kb,
    unsigned short* __restrict__ vt)
{
    const int li = blockIdx.x;
    GEMM_PROLOGUE_512

    if (li < 1024) {
        const int xcd  = li & 7;
        const int slot = li >> 3;            // 0..127
        const int mt   = xcd * 8 + (slot >> 4);
        const int nt   = slot & 15;          // 0..15 across Wq|Wk
        const int m0   = mt * 256;

        k_loop_512(Xb, DA, Wb, DA, m0, nt * 128, DA, Xs, Ws,
                   tid, wm, wn, qq, r, swz, acc);

        unsigned short* Y = (nt >> 3) ? kb : qb;
        const int nc = (nt & 7) * 128;
        EPILOGUE_LOOP({
            Y[(size_t)(m0 + row) * DA + (nc + col)] = f2bf(val);
        })
    } else {
        const int vi  = li - 1024;           // 0..511
        const int xcd = vi & 7;
        const int w   = vi >> 3;             // 0..63
        const int m0  = (xcd * 8 + (w >> 3)) * 256;
        const int n0  = (w & 7) * 128;

        k_loop_512(Xb, DA, Wb + (size_t)2048 * DA, DA, m0, n0, DA, Xs, Ws,
                   tid, wm, wn, qq, r, swz, acc);
        EPILOGUE_VT(vt, m0, n0)
    }
}

// ---------------------------------------------------------------------------
// S = Q.K^T / 32 (lower-tri, packed).  Flat 1D grid 272*G, 512 threads,
// 256x128 tiles, XCD-chunked: u = (bid&7)*C + (bid>>3), C = 34*G;
// bz = u/272, t = u%272; triangular decode yr(yr+1) <= t < (yr+1)(yr+2),
// x = t - yr(yr+1).  Consecutive in-XCD tasks share the 512KB Q panel.
// Rows span packed blocks 2yr, 2yr+1 (different ld) -> per-element y128/ld;
// col guard drops dead half of boundary tile x == 2yr+1.
// ---------------------------------------------------------------------------
__global__ __launch_bounds__(512) void s_gemm(
    const unsigned short* __restrict__ qb, const unsigned short* __restrict__ kb,
    unsigned short* __restrict__ sbuf, int bbase, int C)
{
    const int bid = blockIdx.x;
    const int u   = (bid & 7) * C + (bid >> 3);
    const int bz  = u / 272;
    const int t   = u - bz * 272;

    int yr = (int)((__fsqrt_rn(4.f * (float)t + 1.f) - 1.f) * 0.5f);
    while ((yr + 1) * (yr + 2) <= t) ++yr;      // exact fixup
    while (yr * (yr + 1) > t) --yr;
    const int x = t - yr * (yr + 1);
    const int b = bbase + bz;
    const unsigned short* Am = qb + (size_t)b * T_SEQ * DA;
    const unsigned short* Bm = kb + (size_t)b * T_SEQ * DA;
    const int m0 = yr * 256;
    const int n0 = x * 128;

    GEMM_PROLOGUE_512
    k_loop_512(Am, DA, Bm, DA, m0, n0, DA, Xs, Ws,
               tid, wm, wn, qq, r, swz, acc);

    unsigned short* Sz = sbuf + (size_t)bz * SB_ELEMS;
    EPILOGUE_LOOP({
        const int grow = m0 + row;
        const int y128 = grow >> 7;
        const int ld   = (y128 + 1) * 128;
        const int colg = n0 + col;
        if (colg < ld)
            Sz[(size_t)(y128 * (y128 + 1) / 2) * 16384
               + (size_t)(grow & 127) * ld + colg] = f2bf(val * 0.03125f);
    })
}

// ---------------------------------------------------------------------------
// Row softmax on packed S. grid (4096, G); big rows first.
// ---------------------------------------------------------------------------
__global__ __launch_bounds__(256) void softmax_rows(unsigned short* __restrict__ sbuf)
{
    __shared__ float row[4096];
    __shared__ float red[4];
    const int q   = 4095 - (int)blockIdx.x;
    const int n   = q + 1;
    const int tid = threadIdx.x;
    const int y   = q >> 7;
    const int ld  = (y + 1) * 128;
    unsigned short* rp = sbuf + (size_t)blockIdx.y * SB_ELEMS
                       + (size_t)(y * (y + 1) / 2) * 16384
                       + (size_t)(q & 127) * ld;
    const int n8 = n & ~7;

    for (int i0 = tid * 8; i0 < n8; i0 += 2048) {
        const uint4 v = *(const uint4*)(rp + i0);
        *(float4*)&row[i0]     = make_float4(bflo(v.x), bfhi(v.x), bflo(v.y), bfhi(v.y));
        *(float4*)&row[i0 + 4] = make_float4(bflo(v.z), bfhi(v.z), bflo(v.w), bfhi(v.w));
    }
    for (int i = n8 + tid; i < n; i += 256)
        row[i] = __builtin_bit_cast(float, (unsigned)rp[i] << 16);
    __syncthreads();

    float m = -1e30f;
    for (int i = tid; i < n; i += 256) m = fmaxf(m, row[i]);
    #pragma unroll
    for (int off = 32; off >= 1; off >>= 1) m = fmaxf(m, __shfl_xor(m, off, 64));
    if ((tid & 63) == 0) red[tid >> 6] = m;
    __syncthreads();
    m = fmaxf(fmaxf(red[0], red[1]), fmaxf(red[2], red[3]));
    __syncthreads();

    float s = 0.f;
    for (int i = tid; i < n; i += 256) {
        const float e = __expf(row[i] - m);
        row[i] = e;
        s += e;
    }
    #pragma unroll
    for (int off = 32; off >= 1; off >>= 1) s += __shfl_xor(s, off, 64);
    if ((tid & 63) == 0) red[tid >> 6] = s;
    __syncthreads();
    s = red[0] + red[1] + red[2] + red[3];
    const float inv = 1.f / s;

    for (int i0 = tid * 8; i0 < n8; i0 += 2048) {
        const float4 f0 = *(const float4*)&row[i0];
        const float4 f1 = *(const float4*)&row[i0 + 4];
        uint4 pk;
        pk.x = pack2(f0.x * inv, f0.y * inv);
        pk.y = pack2(f0.z * inv, f0.w * inv);
        pk.z = pack2(f1.x * inv, f1.y * inv);
        pk.w = pack2(f1.z * inv, f1.w * inv);
        *(uint4*)(rp + i0) = pk;
    }
    for (int i = n8 + tid; i < ld; i += 256)
        rp[i] = (i < n) ? f2bf(row[i] * inv) : (unsigned short)0;
}

// ---------------------------------------------------------------------------
// out = P.Vt^T, K = (y+1)*128. grid (8, 32*G), 256 threads, 128x128.
// G==4 (gridDim.y==128): XCD-locality mapping -- w = bx + 8*(by>>3),
//   n0 = (by&7)*128.  bid&7 = w&7 => the 8 n0-siblings of one w (sharing the
//   P panel) land on ONE XCD, 8 distinct CUs => P hot in that XCD's L2.
//   Each CU hosts the full quad {31-i,16+i,15-i,i}, i = bx => 66 K-units/CU.
// G<4 fallback: legacy interleave.
// ---------------------------------------------------------------------------
__global__ __launch_bounds__(256) void o_gemm(
    const unsigned short* __restrict__ sbuf, const unsigned short* __restrict__ vt,
    float* __restrict__ out, int bbase)
{
    const int by = blockIdx.y;
    int y, z, n0;
    if (gridDim.y == 128) {
        const int w  = blockIdx.x + 8 * (by >> 3);   // 0..127 slot-major
        n0 = (by & 7) * 128;
        const int s  = w & 31;
        const int rq = w >> 5;
        const int i  = s & 7;
        z = s >> 3;
        y = (rq == 0) ? (31 - i) : (rq == 1) ? (16 + i)
          : (rq == 2) ? (15 - i) : i;
    } else {
        n0 = blockIdx.x * 128;
        const int gy = by & 31;
        z = by >> 5;
        y = (gy & 1) ? (gy >> 1) : (31 - (gy >> 1));
    }
    const int b  = bbase + z;
    const int K_len = (y + 1) * 128;
    const unsigned short* A  = sbuf + (size_t)z * SB_ELEMS
                             + (size_t)(y * (y + 1) / 2) * 16384;
    const unsigned short* Bv = vt + (size_t)b * T_SEQ * DA;   // [1024][4096]

    GEMM_PROLOGUE_256
    k_loop_256(A, K_len, Bv, T_SEQ, 0, n0, K_len, Xs, Ws,
               tid, wm, wn, qq, r, swz, acc);

    float* outb = out + (size_t)b * T_SEQ * DA + (size_t)y * 128 * DA;
    EPILOGUE_LOOP({
        outb[(size_t)row * DA + (n0 + col)] = rintf(val * 1e4f) * 1e-4f;
    })
}

// ---------------------------------------------------------------------------
extern "C" void kernel_launch(void* const* d_in, const int* in_sizes, int n_in,
                              void* d_out, int out_size, void* d_ws, size_t ws_size,
                              hipStream_t stream)
{
    const float* X  = (const float*)d_in[0];
    const float* Wq = (const float*)d_in[1];
    const float* Wk = (const float*)d_in[2];
    const float* Wv = (const float*)d_in[3];
    float* out = (float*)d_out;

    unsigned short* qb   = (unsigned short*)d_ws;          // [16384,1024]
    unsigned short* kb   = qb + (size_t)M_TOT * DA;
    unsigned short* vt   = kb + (size_t)M_TOT * DA;        // [4][1024][4096]
    unsigned short* sbuf = vt + (size_t)M_TOT * DA;        // G * SB_ELEMS

    // bf16 copies of X / W live in d_out (64 MB), dead after proj_qkv.
    unsigned short* Xb = (unsigned short*)d_out;           // 32 MB
    unsigned short* Wb = Xb + (size_t)M_TOT * DA;          // 6 MB ([3*1024][1024])

    const size_t fixed = (size_t)3 * M_TOT * DA * 2;
    int G = 1;
    if (ws_size >= fixed + (size_t)4 * SB_ELEMS * 2) G = 4;
    else if (ws_size >= fixed + (size_t)2 * SB_ELEMS * 2) G = 2;

    to_bf16_all<<<9728, 256, 0, stream>>>(X, Wq, Wk, Wv, Xb, Wb);
    proj_qkv<<<1536, 512, 0, stream>>>(Xb, Wb, qb, kb, vt);

    for (int b0 = 0; b0 < BATCH; b0 += G) {
        s_gemm<<<272 * G, 512, 0, stream>>>(qb, kb, sbuf, b0, 34 * G);
        softmax_rows<<<dim3(4096, G), 256, 0, stream>>>(sbuf);
        o_gemm<<<dim3(8, 32 * G), 256, 0, stream>>>(sbuf, vt, out, b0);
    }
}